// Round 1
// baseline (579.781 us; speedup 1.0000x reference)
//
#include <hip/hip_runtime.h>
#include <hip/hip_bf16.h>

#define NN 65536
#define NE 524288
#define DF 128
#define NG 512
#define NCLS 10

typedef __bf16 bf16x8 __attribute__((ext_vector_type(8)));
typedef float f32x4 __attribute__((ext_vector_type(4)));
typedef ushort u16x8 __attribute__((ext_vector_type(8)));

__device__ __forceinline__ float bl(uint x) { return __uint_as_float(x << 16); }
__device__ __forceinline__ float bh(uint x) { return __uint_as_float(x & 0xffff0000u); }
__device__ __forceinline__ float b2f(ushort x) { return __uint_as_float((uint)x << 16); }
__device__ __forceinline__ ushort f2b(float f) {
    uint u = __float_as_uint(f);
    return (ushort)((u + 0x7fffu + ((u >> 16) & 1u)) >> 16);  // RN-even
}

// ---------------- degree histograms ----------------
__global__ void k_degrees(const int* __restrict__ src, const int* __restrict__ dst,
                          int* __restrict__ deg_out, int* __restrict__ deg_in) {
    int e = blockIdx.x * blockDim.x + threadIdx.x;
    if (e < NE) {
        atomicAdd(&deg_out[src[e]], 1);
        atomicAdd(&deg_in[dst[e]], 1);
    }
}

__global__ void k_norms(const int* __restrict__ deg_out, const int* __restrict__ deg_in,
                        float* __restrict__ ns, float* __restrict__ nd) {
    int v = blockIdx.x * blockDim.x + threadIdx.x;
    if (v < NN) {
        ns[v] = rsqrtf((float)max(deg_out[v], 1));
        nd[v] = rsqrtf((float)max(deg_in[v], 1));
    }
}

// exclusive scan of deg_in (NN ints) -> rp[0..NN]
__global__ void k_scan(const int* __restrict__ deg, int* __restrict__ rp) {
    __shared__ int tmp[1024];
    int t = threadIdx.x;
    int base = t * 64;
    int s = 0;
    for (int i = 0; i < 64; i++) s += deg[base + i];
    tmp[t] = s;
    __syncthreads();
    for (int off = 1; off < 1024; off <<= 1) {
        int v = (t >= off) ? tmp[t - off] : 0;
        __syncthreads();
        tmp[t] += v;
        __syncthreads();
    }
    int run = tmp[t] - s;
    for (int i = 0; i < 64; i++) {
        int d = deg[base + i];
        rp[base + i] = run;
        run += d;
    }
    if (t == 1023) rp[NN] = run;
}

__global__ void k_scatter(const int* __restrict__ src, const int* __restrict__ dst,
                          const int* __restrict__ rp, int* __restrict__ cursor,
                          int* __restrict__ col) {
    int e = blockIdx.x * blockDim.x + threadIdx.x;
    if (e < NE) {
        int d = dst[e];
        int p = atomicAdd(&cursor[d], 1);
        col[rp[d] + p] = src[e];
    }
}

// xs(bf16) = hx * norm_src; one dword (2 elems) per thread
__global__ void k_scale(const float* __restrict__ hx, const float* __restrict__ ns,
                        uint* __restrict__ xs) {
    int i = blockIdx.x * blockDim.x + threadIdx.x;  // over NN*64 dwords
    float2 v = ((const float2*)hx)[i];
    float s = ns[i >> 6];
    xs[i] = (uint)f2b(v.x * s) | ((uint)f2b(v.y * s) << 16);
}

// W (fp32 [k][n]) -> Wt (bf16 [n][k])
__global__ void k_wconv(const float* __restrict__ W, ushort* __restrict__ Wt) {
    int t = blockIdx.x * blockDim.x + threadIdx.x;  // 16384
    int n = t >> 7, k = t & 127;
    Wt[n * 128 + k] = f2b(W[k * 128 + n]);
}

// ---------------------------------------------------------------------------
// Fused: out = relu( (norm_dst * gather-sum(xs)) @ W + b ) * (scale? ns : 1)
// ONE wave per block, 16 node rows, grid = NN/16 = 4096 blocks.
//   - latency-bound gather: 1-wave blocks let the dispatcher backfill around
//     slow (high-degree / miss-heavy) waves; grid residency 2x vs 4-wave blocks
//   - unroll-4 edge loop: 16 uint4 loads in flight per lane (2x MLP)
// Lane (l&15)=row, (l>>4)=k-quad. No __syncthreads needed (wave-private LDS).
// ---------------------------------------------------------------------------
#define UNP(k, v) { a[k][0] += bl(v.x); a[k][1] += bh(v.x); \
                    a[k][2] += bl(v.y); a[k][3] += bh(v.y); \
                    a[k][4] += bl(v.z); a[k][5] += bh(v.z); \
                    a[k][6] += bl(v.w); a[k][7] += bh(v.w); }

__global__ __launch_bounds__(64, 4) void k_fused(
        const uint4* __restrict__ X,      // xs as uint4 rows: node*16 chunks
        const int* __restrict__ rp, const int* __restrict__ col,
        const float* __restrict__ nd, const float* __restrict__ ns,
        const uint4* __restrict__ Wg,     // Wt bf16 [n][k] as uint4: n*16+chunk
        const float* __restrict__ b, int do_scale,
        ushort* __restrict__ out) {
    __shared__ ushort Cs[16 * 128];       // 4 KB, wave-private
    int lane = threadIdx.x;
    int r = lane & 15;      // row within wave tile / col within C tile
    int q = lane >> 4;      // k-quad (gather) / row-quad (C)
    int nb = blockIdx.x * 16;             // first node of this wave
    int node = nb + r;

    int s = rp[node], e = rp[node + 1];
    float a[4][8] = {};
    int i = s;
    for (; i + 4 <= e; i += 4) {
        int c0 = col[i], c1 = col[i + 1], c2 = col[i + 2], c3 = col[i + 3];
        const uint4* p0 = X + (size_t)c0 * 16 + q;
        const uint4* p1 = X + (size_t)c1 * 16 + q;
        const uint4* p2 = X + (size_t)c2 * 16 + q;
        const uint4* p3 = X + (size_t)c3 * 16 + q;
        uint4 x0 = p0[0], x1 = p0[4], x2 = p0[8], x3 = p0[12];
        uint4 y0 = p1[0], y1 = p1[4], y2 = p1[8], y3 = p1[12];
        uint4 z0 = p2[0], z1 = p2[4], z2 = p2[8], z3 = p2[12];
        uint4 u0 = p3[0], u1 = p3[4], u2 = p3[8], u3 = p3[12];
        UNP(0, x0) UNP(1, x1) UNP(2, x2) UNP(3, x3)
        UNP(0, y0) UNP(1, y1) UNP(2, y2) UNP(3, y3)
        UNP(0, z0) UNP(1, z1) UNP(2, z2) UNP(3, z3)
        UNP(0, u0) UNP(1, u1) UNP(2, u2) UNP(3, u3)
    }
    for (; i + 2 <= e; i += 2) {
        size_t b0 = (size_t)col[i] * 16 + q;
        size_t b1 = (size_t)col[i + 1] * 16 + q;
        uint4 x0 = X[b0],      y0 = X[b1];
        uint4 x1 = X[b0 + 4],  y1 = X[b1 + 4];
        uint4 x2 = X[b0 + 8],  y2 = X[b1 + 8];
        uint4 x3 = X[b0 + 12], y3 = X[b1 + 12];
        UNP(0, x0) UNP(1, x1) UNP(2, x2) UNP(3, x3)
        UNP(0, y0) UNP(1, y1) UNP(2, y2) UNP(3, y3)
    }
    if (i < e) {
        size_t b0 = (size_t)col[i] * 16 + q;
        uint4 x0 = X[b0], x1 = X[b0 + 4], x2 = X[b0 + 8], x3 = X[b0 + 12];
        UNP(0, x0) UNP(1, x1) UNP(2, x2) UNP(3, x3)
    }

    // convert to bf16 A-fragments (scale by norm_dst)
    float sc = nd[node];
    bf16x8 afr[4];
    #pragma unroll
    for (int ks = 0; ks < 4; ks++) {
        union { u16x8 u; bf16x8 f; } cv;
        #pragma unroll
        for (int j = 0; j < 8; j++) cv.u[j] = f2b(a[ks][j] * sc);
        afr[ks] = cv.f;
    }

    // MFMA: C[16 rows][128 cols], W fragments straight from global (L2-hot)
    f32x4 cacc[8] = {};
    #pragma unroll
    for (int ks = 0; ks < 4; ks++) {
        #pragma unroll
        for (int ni = 0; ni < 8; ni++) {
            union { uint4 u; bf16x8 f; } bw;
            bw.u = Wg[(size_t)(ni * 16 + r) * 16 + ks * 4 + q];
            cacc[ni] = __builtin_amdgcn_mfma_f32_16x16x32_bf16(
                afr[ks], bw.f, cacc[ni], 0, 0, 0);
        }
    }

    // epilogue: bias + relu + (ns fold) -> bf16, via wave-private LDS for
    // coalesced 16B global stores
    float sc4[4];
    #pragma unroll
    for (int rg = 0; rg < 4; rg++)
        sc4[rg] = do_scale ? ns[nb + q * 4 + rg] : 1.f;
    #pragma unroll
    for (int ni = 0; ni < 8; ni++) {
        int c = ni * 16 + r;
        float bb = b[c];
        #pragma unroll
        for (int rg = 0; rg < 4; rg++) {
            float v = fmaxf(cacc[ni][rg] + bb, 0.f) * sc4[rg];
            Cs[(q * 4 + rg) * 128 + c] = f2b(v);
        }
    }
    const uint4* Cs4 = (const uint4*)Cs;
    uint4* Og = (uint4*)(out + (size_t)nb * 128);
    #pragma unroll
    for (int it = 0; it < 4; it++)
        Og[it * 64 + lane] = Cs4[it * 64 + lane];
}

// graph row pointers via binary search on sorted graph_id
__global__ void k_gptr(const int* __restrict__ gid, int* __restrict__ gptr) {
    int g = blockIdx.x * blockDim.x + threadIdx.x;
    if (g <= NG) {
        int lo = 0, hi = NN;
        while (lo < hi) {
            int mid = (lo + hi) >> 1;
            if (gid[mid] < g) lo = mid + 1; else hi = mid;
        }
        gptr[g] = lo;
    }
}

// mean-pool: block per graph, 256 threads, dword loads, 4-way row parallel
__global__ __launch_bounds__(256) void k_pool(
        const uint* __restrict__ h, const int* __restrict__ gptr,
        float* __restrict__ pooled) {
    __shared__ float2 part[256];
    int g = blockIdx.x, t = threadIdx.x;
    int d = t & 63, qq = t >> 6;
    int s = gptr[g], e = gptr[g + 1];
    float2 acc = make_float2(0.f, 0.f);
    for (int i = s + qq; i < e; i += 4) {
        uint x = h[(size_t)i * 64 + d];
        acc.x += bl(x); acc.y += bh(x);
    }
    part[t] = acc;
    __syncthreads();
    if (t < 64) {
        float2 p0 = part[t], p1 = part[t + 64], p2 = part[t + 128], p3 = part[t + 192];
        float inv = 1.f / fmaxf((float)(e - s), 1.f);
        ((float2*)(pooled + g * 128))[t] =
            make_float2((p0.x + p1.x + p2.x + p3.x) * inv,
                        (p0.y + p1.y + p2.y + p3.y) * inv);
    }
}

__global__ __launch_bounds__(64) void k_head(
        const float* __restrict__ pooled,
        const float* __restrict__ Wp1, const float* __restrict__ bp1,
        const float* __restrict__ Wp2, const float* __restrict__ bp2,
        float* __restrict__ scores) {
    __shared__ float p[128];
    __shared__ float t1[64];
    int g = blockIdx.x, t = threadIdx.x;
    p[t] = pooled[g * 128 + t];
    p[t + 64] = pooled[g * 128 + 64 + t];
    __syncthreads();
    float a = 0.f;
    for (int k = 0; k < 128; k++) a += p[k] * Wp1[k * 64 + t];
    t1[t] = fmaxf(a + bp1[t], 0.f);
    __syncthreads();
    if (t < NCLS) {
        float s = bp2[t];
        for (int k = 0; k < 64; k++) s += t1[k] * Wp2[k * NCLS + t];
        scores[g * NCLS + t] = s;
    }
}

extern "C" void kernel_launch(void* const* d_in, const int* in_sizes, int n_in,
                              void* d_out, int out_size, void* d_ws, size_t ws_size,
                              hipStream_t stream) {
    const float* hx  = (const float*)d_in[0];
    const int*   src = (const int*)d_in[1];
    const int*   dst = (const int*)d_in[2];
    const int*   gid = (const int*)d_in[3];
    const float* Ws[6], *bs[6];
    for (int l = 0; l < 6; l++) {
        Ws[l] = (const float*)d_in[5 + 2 * l];
        bs[l] = (const float*)d_in[6 + 2 * l];
    }
    const float* Wp1 = (const float*)d_in[17];
    const float* bp1 = (const float*)d_in[18];
    const float* Wp2 = (const float*)d_in[19];
    const float* bp2 = (const float*)d_in[20];
    float* scores = (float*)d_out;

    // ---- workspace layout (16B-aligned chunks) ----
    char* w = (char*)d_ws;
    ushort* xsA = (ushort*)w;     w += (size_t)NN * DF * 2;        // 16 MB
    ushort* xsB = (ushort*)w;     w += (size_t)NN * DF * 2;        // 16 MB
    ushort* Wt = (ushort*)w;      w += (size_t)6 * 128 * 128 * 2;  // 192 KB
    int* deg_in  = (int*)w;       w += NN * 4;
    int* deg_out = (int*)w;       w += NN * 4;
    int* cursor  = (int*)w;       w += NN * 4;
    int* rp      = (int*)w;       w += (NN + 1) * 4 + 12;
    int* colv    = (int*)w;       w += NE * 4;
    float* ns    = (float*)w;     w += NN * 4;
    float* ndst  = (float*)w;     w += NN * 4;
    int* gptr    = (int*)w;       w += (NG + 1) * 4 + 12;
    float* pooled = (float*)w;    w += NG * DF * 4;

    hipMemsetAsync(deg_in, 0, (size_t)NN * 4 * 3, stream);  // deg_in/deg_out/cursor

    k_degrees<<<NE / 256, 256, 0, stream>>>(src, dst, deg_out, deg_in);
    k_norms<<<NN / 256, 256, 0, stream>>>(deg_out, deg_in, ns, ndst);
    k_scan<<<1, 1024, 0, stream>>>(deg_in, rp);
    k_scatter<<<NE / 256, 256, 0, stream>>>(src, dst, rp, cursor, colv);
    k_scale<<<NN * 64 / 256, 256, 0, stream>>>(hx, ns, (uint*)xsA);
    for (int l = 0; l < 6; l++)
        k_wconv<<<64, 256, 0, stream>>>(Ws[l], Wt + (size_t)l * 128 * 128);

    ushort* cur = xsA;
    ushort* nxt = xsB;
    for (int l = 0; l < 6; l++) {
        k_fused<<<NN / 16, 64, 0, stream>>>(
            (const uint4*)cur, rp, colv, ndst, ns,
            (const uint4*)(Wt + (size_t)l * 128 * 128), bs[l],
            (l < 5) ? 1 : 0, nxt);
        ushort* tmp = cur; cur = nxt; nxt = tmp;
    }

    k_gptr<<<3, 256, 0, stream>>>(gid, gptr);
    k_pool<<<NG, 256, 0, stream>>>((const uint*)cur, gptr, pooled);
    k_head<<<NG, 64, 0, stream>>>(pooled, Wp1, bp1, Wp2, bp2, scores);
}

// Round 2
// 375.232 us; speedup vs baseline: 1.5451x; 1.5451x over previous
//
#include <hip/hip_runtime.h>
#include <hip/hip_bf16.h>

#define NN 65536
#define NE 524288
#define DF 128
#define NG 512
#define NCLS 10

typedef __bf16 bf16x8 __attribute__((ext_vector_type(8)));
typedef float f32x4 __attribute__((ext_vector_type(4)));
typedef ushort u16x8 __attribute__((ext_vector_type(8)));

__device__ __forceinline__ float bl(uint x) { return __uint_as_float(x << 16); }
__device__ __forceinline__ float bh(uint x) { return __uint_as_float(x & 0xffff0000u); }
__device__ __forceinline__ float b2f(ushort x) { return __uint_as_float((uint)x << 16); }
__device__ __forceinline__ ushort f2b(float f) {
    uint u = __float_as_uint(f);
    return (ushort)((u + 0x7fffu + ((u >> 16) & 1u)) >> 16);  // RN-even
}

// ---------------- degree histograms ----------------
__global__ void k_degrees(const int* __restrict__ src, const int* __restrict__ dst,
                          int* __restrict__ deg_out, int* __restrict__ deg_in) {
    int e = blockIdx.x * blockDim.x + threadIdx.x;
    if (e < NE) {
        atomicAdd(&deg_out[src[e]], 1);
        atomicAdd(&deg_in[dst[e]], 1);
    }
}

__global__ void k_norms(const int* __restrict__ deg_out, const int* __restrict__ deg_in,
                        float* __restrict__ ns, float* __restrict__ nd) {
    int v = blockIdx.x * blockDim.x + threadIdx.x;
    if (v < NN) {
        ns[v] = rsqrtf((float)max(deg_out[v], 1));
        nd[v] = rsqrtf((float)max(deg_in[v], 1));
    }
}

// exclusive scan of deg_in (NN ints) -> rp[0..NN]
__global__ void k_scan(const int* __restrict__ deg, int* __restrict__ rp) {
    __shared__ int tmp[1024];
    int t = threadIdx.x;
    int base = t * 64;
    int s = 0;
    for (int i = 0; i < 64; i++) s += deg[base + i];
    tmp[t] = s;
    __syncthreads();
    for (int off = 1; off < 1024; off <<= 1) {
        int v = (t >= off) ? tmp[t - off] : 0;
        __syncthreads();
        tmp[t] += v;
        __syncthreads();
    }
    int run = tmp[t] - s;
    for (int i = 0; i < 64; i++) {
        int d = deg[base + i];
        rp[base + i] = run;
        run += d;
    }
    if (t == 1023) rp[NN] = run;
}

__global__ void k_scatter(const int* __restrict__ src, const int* __restrict__ dst,
                          const int* __restrict__ rp, int* __restrict__ cursor,
                          int* __restrict__ col) {
    int e = blockIdx.x * blockDim.x + threadIdx.x;
    if (e < NE) {
        int d = dst[e];
        int p = atomicAdd(&cursor[d], 1);
        col[rp[d] + p] = src[e];
    }
}

// xs(bf16) = hx * norm_src; one dword (2 elems) per thread
__global__ void k_scale(const float* __restrict__ hx, const float* __restrict__ ns,
                        uint* __restrict__ xs) {
    int i = blockIdx.x * blockDim.x + threadIdx.x;  // over NN*64 dwords
    float2 v = ((const float2*)hx)[i];
    float s = ns[i >> 6];
    xs[i] = (uint)f2b(v.x * s) | ((uint)f2b(v.y * s) << 16);
}

// W (fp32 [k][n]) -> Wt (bf16 [n][k])
__global__ void k_wconv(const float* __restrict__ W, ushort* __restrict__ Wt) {
    int t = blockIdx.x * blockDim.x + threadIdx.x;  // 16384
    int n = t >> 7, k = t & 127;
    Wt[n * 128 + k] = f2b(W[k * 128 + n]);
}

// ---------------------------------------------------------------------------
// Fused: out = relu( (norm_dst * gather-sum(xs)) @ W + b ) * (scale? ns : 1)
// ONE wave per block, 16 node rows, grid = NN/16 = 4096 blocks.
//   - 1-wave blocks: fine dispatch granularity, backfill around slow waves
//     (R1: occupancy 18.6% -> 33.4%, kept)
//   - unroll-2 gather: 8 uint4 in flight = ~72 VGPR footprint, NO spills
//     (R1 post-mortem: unroll-4 + launch_bounds(64,4) capped VGPR at 64 ->
//      ~93 MB/dispatch scratch writes; reverted)
// Lane (l&15)=row, (l>>4)=k-quad. No __syncthreads needed (wave-private LDS).
// ---------------------------------------------------------------------------
#define UNP(k, v) { a[k][0] += bl(v.x); a[k][1] += bh(v.x); \
                    a[k][2] += bl(v.y); a[k][3] += bh(v.y); \
                    a[k][4] += bl(v.z); a[k][5] += bh(v.z); \
                    a[k][6] += bl(v.w); a[k][7] += bh(v.w); }

__global__ __launch_bounds__(64, 2) void k_fused(
        const uint4* __restrict__ X,      // xs as uint4 rows: node*16 chunks
        const int* __restrict__ rp, const int* __restrict__ col,
        const float* __restrict__ nd, const float* __restrict__ ns,
        const uint4* __restrict__ Wg,     // Wt bf16 [n][k] as uint4: n*16+chunk
        const float* __restrict__ b, int do_scale,
        ushort* __restrict__ out) {
    __shared__ ushort Cs[16 * 128];       // 4 KB, wave-private
    int lane = threadIdx.x;
    int r = lane & 15;      // row within wave tile / col within C tile
    int q = lane >> 4;      // k-quad (gather) / row-quad (C)
    int nb = blockIdx.x * 16;             // first node of this wave
    int node = nb + r;

    int s = rp[node], e = rp[node + 1];
    float a[4][8] = {};
    int i = s;
    for (; i + 2 <= e; i += 2) {
        size_t b0 = (size_t)col[i] * 16 + q;
        size_t b1 = (size_t)col[i + 1] * 16 + q;
        uint4 x0 = X[b0],      y0 = X[b1];
        uint4 x1 = X[b0 + 4],  y1 = X[b1 + 4];
        uint4 x2 = X[b0 + 8],  y2 = X[b1 + 8];
        uint4 x3 = X[b0 + 12], y3 = X[b1 + 12];
        UNP(0, x0) UNP(1, x1) UNP(2, x2) UNP(3, x3)
        UNP(0, y0) UNP(1, y1) UNP(2, y2) UNP(3, y3)
    }
    if (i < e) {
        size_t b0 = (size_t)col[i] * 16 + q;
        uint4 x0 = X[b0], x1 = X[b0 + 4], x2 = X[b0 + 8], x3 = X[b0 + 12];
        UNP(0, x0) UNP(1, x1) UNP(2, x2) UNP(3, x3)
    }

    // convert to bf16 A-fragments (scale by norm_dst)
    float sc = nd[node];
    bf16x8 afr[4];
    #pragma unroll
    for (int ks = 0; ks < 4; ks++) {
        union { u16x8 u; bf16x8 f; } cv;
        #pragma unroll
        for (int j = 0; j < 8; j++) cv.u[j] = f2b(a[ks][j] * sc);
        afr[ks] = cv.f;
    }

    // MFMA: C[16 rows][128 cols], W fragments straight from global (L2-hot)
    f32x4 cacc[8] = {};
    #pragma unroll
    for (int ks = 0; ks < 4; ks++) {
        #pragma unroll
        for (int ni = 0; ni < 8; ni++) {
            union { uint4 u; bf16x8 f; } bw;
            bw.u = Wg[(size_t)(ni * 16 + r) * 16 + ks * 4 + q];
            cacc[ni] = __builtin_amdgcn_mfma_f32_16x16x32_bf16(
                afr[ks], bw.f, cacc[ni], 0, 0, 0);
        }
    }

    // epilogue: bias + relu + (ns fold) -> bf16, via wave-private LDS for
    // coalesced 16B global stores
    float sc4[4];
    #pragma unroll
    for (int rg = 0; rg < 4; rg++)
        sc4[rg] = do_scale ? ns[nb + q * 4 + rg] : 1.f;
    #pragma unroll
    for (int ni = 0; ni < 8; ni++) {
        int c = ni * 16 + r;
        float bb = b[c];
        #pragma unroll
        for (int rg = 0; rg < 4; rg++) {
            float v = fmaxf(cacc[ni][rg] + bb, 0.f) * sc4[rg];
            Cs[(q * 4 + rg) * 128 + c] = f2b(v);
        }
    }
    const uint4* Cs4 = (const uint4*)Cs;
    uint4* Og = (uint4*)(out + (size_t)nb * 128);
    #pragma unroll
    for (int it = 0; it < 4; it++)
        Og[it * 64 + lane] = Cs4[it * 64 + lane];
}

// graph row pointers via binary search on sorted graph_id
__global__ void k_gptr(const int* __restrict__ gid, int* __restrict__ gptr) {
    int g = blockIdx.x * blockDim.x + threadIdx.x;
    if (g <= NG) {
        int lo = 0, hi = NN;
        while (lo < hi) {
            int mid = (lo + hi) >> 1;
            if (gid[mid] < g) lo = mid + 1; else hi = mid;
        }
        gptr[g] = lo;
    }
}

// mean-pool: block per graph, 256 threads, dword loads, 4-way row parallel
__global__ __launch_bounds__(256) void k_pool(
        const uint* __restrict__ h, const int* __restrict__ gptr,
        float* __restrict__ pooled) {
    __shared__ float2 part[256];
    int g = blockIdx.x, t = threadIdx.x;
    int d = t & 63, qq = t >> 6;
    int s = gptr[g], e = gptr[g + 1];
    float2 acc = make_float2(0.f, 0.f);
    for (int i = s + qq; i < e; i += 4) {
        uint x = h[(size_t)i * 64 + d];
        acc.x += bl(x); acc.y += bh(x);
    }
    part[t] = acc;
    __syncthreads();
    if (t < 64) {
        float2 p0 = part[t], p1 = part[t + 64], p2 = part[t + 128], p3 = part[t + 192];
        float inv = 1.f / fmaxf((float)(e - s), 1.f);
        ((float2*)(pooled + g * 128))[t] =
            make_float2((p0.x + p1.x + p2.x + p3.x) * inv,
                        (p0.y + p1.y + p2.y + p3.y) * inv);
    }
}

__global__ __launch_bounds__(64) void k_head(
        const float* __restrict__ pooled,
        const float* __restrict__ Wp1, const float* __restrict__ bp1,
        const float* __restrict__ Wp2, const float* __restrict__ bp2,
        float* __restrict__ scores) {
    __shared__ float p[128];
    __shared__ float t1[64];
    int g = blockIdx.x, t = threadIdx.x;
    p[t] = pooled[g * 128 + t];
    p[t + 64] = pooled[g * 128 + 64 + t];
    __syncthreads();
    float a = 0.f;
    for (int k = 0; k < 128; k++) a += p[k] * Wp1[k * 64 + t];
    t1[t] = fmaxf(a + bp1[t], 0.f);
    __syncthreads();
    if (t < NCLS) {
        float s = bp2[t];
        for (int k = 0; k < 64; k++) s += t1[k] * Wp2[k * NCLS + t];
        scores[g * NCLS + t] = s;
    }
}

extern "C" void kernel_launch(void* const* d_in, const int* in_sizes, int n_in,
                              void* d_out, int out_size, void* d_ws, size_t ws_size,
                              hipStream_t stream) {
    const float* hx  = (const float*)d_in[0];
    const int*   src = (const int*)d_in[1];
    const int*   dst = (const int*)d_in[2];
    const int*   gid = (const int*)d_in[3];
    const float* Ws[6], *bs[6];
    for (int l = 0; l < 6; l++) {
        Ws[l] = (const float*)d_in[5 + 2 * l];
        bs[l] = (const float*)d_in[6 + 2 * l];
    }
    const float* Wp1 = (const float*)d_in[17];
    const float* bp1 = (const float*)d_in[18];
    const float* Wp2 = (const float*)d_in[19];
    const float* bp2 = (const float*)d_in[20];
    float* scores = (float*)d_out;

    // ---- workspace layout (16B-aligned chunks) ----
    char* w = (char*)d_ws;
    ushort* xsA = (ushort*)w;     w += (size_t)NN * DF * 2;        // 16 MB
    ushort* xsB = (ushort*)w;     w += (size_t)NN * DF * 2;        // 16 MB
    ushort* Wt = (ushort*)w;      w += (size_t)6 * 128 * 128 * 2;  // 192 KB
    int* deg_in  = (int*)w;       w += NN * 4;
    int* deg_out = (int*)w;       w += NN * 4;
    int* cursor  = (int*)w;       w += NN * 4;
    int* rp      = (int*)w;       w += (NN + 1) * 4 + 12;
    int* colv    = (int*)w;       w += NE * 4;
    float* ns    = (float*)w;     w += NN * 4;
    float* ndst  = (float*)w;     w += NN * 4;
    int* gptr    = (int*)w;       w += (NG + 1) * 4 + 12;
    float* pooled = (float*)w;    w += NG * DF * 4;

    hipMemsetAsync(deg_in, 0, (size_t)NN * 4 * 3, stream);  // deg_in/deg_out/cursor

    k_degrees<<<NE / 256, 256, 0, stream>>>(src, dst, deg_out, deg_in);
    k_norms<<<NN / 256, 256, 0, stream>>>(deg_out, deg_in, ns, ndst);
    k_scan<<<1, 1024, 0, stream>>>(deg_in, rp);
    k_scatter<<<NE / 256, 256, 0, stream>>>(src, dst, rp, cursor, colv);
    k_scale<<<NN * 64 / 256, 256, 0, stream>>>(hx, ns, (uint*)xsA);
    for (int l = 0; l < 6; l++)
        k_wconv<<<64, 256, 0, stream>>>(Ws[l], Wt + (size_t)l * 128 * 128);

    ushort* cur = xsA;
    ushort* nxt = xsB;
    for (int l = 0; l < 6; l++) {
        k_fused<<<NN / 16, 64, 0, stream>>>(
            (const uint4*)cur, rp, colv, ndst, ns,
            (const uint4*)(Wt + (size_t)l * 128 * 128), bs[l],
            (l < 5) ? 1 : 0, nxt);
        ushort* tmp = cur; cur = nxt; nxt = tmp;
    }

    k_gptr<<<3, 256, 0, stream>>>(gid, gptr);
    k_pool<<<NG, 256, 0, stream>>>((const uint*)cur, gptr, pooled);
    k_head<<<NG, 64, 0, stream>>>(pooled, Wp1, bp1, Wp2, bp2, scores);
}